// Round 1
// 2511.173 us; speedup vs baseline: 1.0375x; 1.0375x over previous
//
#include <hip/hip_runtime.h>

// LSTM_RNN: B=8192, T=2048, H=51, 2-layer LSTM + linear head.
// R5: fused o-gate/tanh(c) output path — h = sigma(o)*tanh(c) =
// (1-ec)/((1+eo)(1+ec)) with row-paired rcp: 2 rcp/quad instead of 4 and no
// separate sigma(o) block (saves ~28 issue-cyc/wave-step in BOTH layers);
// tanh-arg clamp tightened to +-30 via v_med3 (keeps the cross-row product
// <= 2^104, f32-safe; saturation err < 1e-9). s_setprio(1) around MFMA
// clusters (T5: L1/L2 wave role diversity on each SIMD). Everything else as
// R4: fp16 MFMA, x/bias folded into K-slots 51/52, paired-rcp sigmoids,
// ROWW=72 LDS rows, producer-consumer wave split, 1 barrier/step.

#define B_TOT 8192
#define T_LEN 2048
#define MR    16
#define ROWW  72            // f16 per row: [h 0..50][x 51][1.0 52][0 ..63][pad]
#define HB    (MR*ROWW)     // 1152 f16 per parity buffer

typedef _Float16 f16x8 __attribute__((ext_vector_type(8)));
typedef float    f32x4 __attribute__((ext_vector_type(4)));

#define LOG2E 1.4426950408889634f

static __device__ __forceinline__ float us2f(unsigned short u) {
    unsigned int w = ((unsigned int)u) << 16;
    float f; __builtin_memcpy(&f, &w, 4);
    return f;
}
// load f32 from f32 or bf16 global
static __device__ __forceinline__ float ldf(const void* p, int idx, bool isbf) {
    return isbf ? us2f(((const unsigned short*)p)[idx])
                : ((const float*)p)[idx];
}
static __device__ __forceinline__ void store_y(void* outp, bool isbf, int idx, float v) {
    if (isbf) {
        unsigned int u; __builtin_memcpy(&u, &v, 4);
        u = (u + 0x7FFFu + ((u >> 16) & 1u)) >> 16;
        ((unsigned short*)outp)[idx] = (unsigned short)u;
    } else {
        ((float*)outp)[idx] = v;
    }
}

__global__ __launch_bounds__(512, 4)
void lstm2_kernel(const void* __restrict__ xin,
                  const void* __restrict__ Wih1, const void* __restrict__ Whh1,
                  const void* __restrict__ bih1, const void* __restrict__ bhh1,
                  const void* __restrict__ Wih2, const void* __restrict__ Whh2,
                  const void* __restrict__ bih2, const void* __restrict__ bhh2,
                  const void* __restrict__ Wlin, const void* __restrict__ blin,
                  void* __restrict__ outp)
{
    const int tid  = threadIdx.x;
    const int wset = tid >> 8;         // 0: layer-1 waves, 1: layer-2 waves
    const int wv   = (tid >> 6) & 3;   // j-slice within set
    const int ln   = tid & 63;
    const int lid  = ln & 15;
    const int quad = ln >> 4;
    const int b0   = blockIdx.x * MR;
    const int jcol = 13*wv + lid;
    const bool valid = (lid < 13) && (jcol < 51);
    const bool ylane = (wv == 3) && (lid == 12);   // pad col 51 -> y head

    __shared__ alignas(16) _Float16 hx [2*HB];   // h1 ping-pong + x/1.0 K-slots
    __shared__ alignas(16) _Float16 h2b[2*HB];   // h2 ping-pong

    // ---- dtype sniff (f32 vs bf16 globals), block-uniform ----
    bool isbf;
    {
        const unsigned short* xu = (const unsigned short*)xin;
        int cnt = 0;
        #pragma unroll
        for (int i = 0; i < 64; i += 2) {
            unsigned e = (xu[i] >> 7) & 0xFFu;
            cnt += (e >= 115u && e <= 131u) ? 1 : 0;
        }
        isbf = (cnt >= 16);
    }

    // ---- init LDS ----
    for (int i = tid; i < 2*HB; i += 512) {
        hx[i]  = (_Float16)0.0f;
        h2b[i] = (_Float16)0.0f;
    }
    __syncthreads();
    if (tid < MR) {
        hx[0*HB + tid*ROWW + 52] = (_Float16)1.0f;   // bias slot, both parities
        hx[1*HB + tid*ROWW + 52] = (_Float16)1.0f;
        hx[1*HB + tid*ROWW + 51] = (_Float16)ldf(xin, (b0 + tid)*T_LEN, isbf);
    }
    __syncthreads();

    if (wset == 0) {
        // ================= LAYER-1 WAVES =================
        // B-frag: k<51 -> sn*Whh1 ; k==51 -> sn*Wih1 (x slot) ; k==52 -> sn*bias
        f16x8 B1[4][2];
        #pragma unroll
        for (int n = 0; n < 4; ++n) {
            const int g = 51*n + jcol;
            const float sn = (n == 2) ? -2.0f*LOG2E : -LOG2E;
            #pragma unroll
            for (int kb = 0; kb < 2; ++kb) {
                f16x8 f;
                #pragma unroll
                for (int j8 = 0; j8 < 8; ++j8) {
                    const int k = kb*32 + quad*8 + j8;
                    float v = 0.0f;
                    if (valid) {
                        if (k < 51)       v = sn * ldf(Whh1, g*51 + k, isbf);
                        else if (k == 51) v = sn * ldf(Wih1, g, isbf);
                        else if (k == 52) v = sn * (ldf(bih1, g, isbf) + ldf(bhh1, g, isbf));
                    }
                    f[j8] = (_Float16)v;
                }
                B1[n][kb] = f;
            }
        }
        float c1[4] = {0,0,0,0};

        #pragma unroll 2
        for (int k = 0; k <= T_LEN; ++k) {
            if (k < T_LEN) {
                const int rs = (k - 1) & 1, ws = k & 1;
                // early x(k+1) prefetch (wave 0 lanes 0..15)
                const bool xl = (tid < MR) && (k + 1 < T_LEN);
                float xnext = 0.0f;
                if (xl) xnext = ldf(xin, (b0 + tid)*T_LEN + k + 1, isbf);

                const _Float16* hp = &hx[rs*HB + lid*ROWW + quad*8];
                const f16x8 a0 = *(const f16x8*)(hp);
                const f16x8 a1 = *(const f16x8*)(hp + 32);
                f32x4 acc[4];
                __builtin_amdgcn_s_setprio(1);
                #pragma unroll
                for (int n = 0; n < 4; ++n) {
                    f32x4 z = {0.0f, 0.0f, 0.0f, 0.0f};
                    z      = __builtin_amdgcn_mfma_f32_16x16x32_f16(a0, B1[n][0], z, 0,0,0);
                    acc[n] = __builtin_amdgcn_mfma_f32_16x16x32_f16(a1, B1[n][1], z, 0,0,0);
                }
                __builtin_amdgcn_s_setprio(0);
                // gates i,f,g: d = 1 + 2^(scaled pre-act); paired rcp
                float s[3][4];
                #pragma unroll
                for (int n = 0; n < 3; ++n) {
                    float d0 = 1.0f + __builtin_amdgcn_exp2f(acc[n][0]);
                    float d1 = 1.0f + __builtin_amdgcn_exp2f(acc[n][1]);
                    float d2 = 1.0f + __builtin_amdgcn_exp2f(acc[n][2]);
                    float d3 = 1.0f + __builtin_amdgcn_exp2f(acc[n][3]);
                    const float Ra = __builtin_amdgcn_rcpf(d0*d1);
                    const float Rb = __builtin_amdgcn_rcpf(d2*d3);
                    if (n == 2) {   // tanh
                        s[n][0] = fmaf(2.0f, Ra*d1, -1.0f);
                        s[n][1] = fmaf(2.0f, Ra*d0, -1.0f);
                        s[n][2] = fmaf(2.0f, Rb*d3, -1.0f);
                        s[n][3] = fmaf(2.0f, Rb*d2, -1.0f);
                    } else {        // sigmoid
                        s[n][0] = Ra*d1; s[n][1] = Ra*d0;
                        s[n][2] = Rb*d3; s[n][3] = Rb*d2;
                    }
                }
                // o-gate: keep denominators only (sigma(o) fused into h below)
                float dox[4];
                #pragma unroll
                for (int r = 0; r < 4; ++r)
                    dox[r] = 1.0f + __builtin_amdgcn_exp2f(acc[3][r]);
                // cell update + fused h = (1-ec)/((1+eo)(1+ec)), row-paired rcp
                float m[4], ec[4];
                #pragma unroll
                for (int r = 0; r < 4; ++r) {
                    const float c = fmaf(s[1][r], c1[r], s[0][r]*s[2][r]);
                    c1[r] = c;
                    const float a = __builtin_amdgcn_fmed3f(-2.0f*LOG2E*c, -30.0f, 30.0f);
                    const float e = __builtin_amdgcn_exp2f(a);
                    ec[r] = e;
                    m[r]  = dox[r] * (1.0f + e);
                }
                const float Rc = __builtin_amdgcn_rcpf(m[0]*m[1]);
                const float Rd = __builtin_amdgcn_rcpf(m[2]*m[3]);
                float h[4];
                h[0] = (1.0f - ec[0]) * (Rc * m[1]);
                h[1] = (1.0f - ec[1]) * (Rc * m[0]);
                h[2] = (1.0f - ec[2]) * (Rd * m[3]);
                h[3] = (1.0f - ec[3]) * (Rd * m[2]);
                if (valid) {
                    #pragma unroll
                    for (int r = 0; r < 4; ++r)
                        hx[ws*HB + (quad*4 + r)*ROWW + jcol] = (_Float16)h[r];
                }
                if (xl) hx[ws*HB + tid*ROWW + 51] = (_Float16)xnext;
            }
            __syncthreads();
        }
    } else {
        // ================= LAYER-2 WAVES =================
        // B2i over h1-path A (k<51: Wih2; k==51: 0 kills x slot; k==52: bias
        // [or blin on y pad col]); B2h over h2-path A (k<51: Whh2 [or Wlin]).
        f16x8 B2i[4][2], B2h[4][2];
        #pragma unroll
        for (int n = 0; n < 4; ++n) {
            const int g = 51*n + jcol;
            const float sn = (n == 2) ? -2.0f*LOG2E : -LOG2E;
            #pragma unroll
            for (int kb = 0; kb < 2; ++kb) {
                f16x8 fi, fh;
                #pragma unroll
                for (int j8 = 0; j8 < 8; ++j8) {
                    const int k = kb*32 + quad*8 + j8;
                    float vi = 0.0f, vh = 0.0f;
                    if (valid) {
                        if (k < 51) {
                            vi = sn * ldf(Wih2, g*51 + k, isbf);
                            vh = sn * ldf(Whh2, g*51 + k, isbf);
                        } else if (k == 52) {
                            vi = sn * (ldf(bih2, g, isbf) + ldf(bhh2, g, isbf));
                        }
                    } else if (ylane && n == 3) {
                        if (k < 51)       vh = ldf(Wlin, k, isbf);
                        else if (k == 52) vi = ldf(blin, 0, isbf);
                    }
                    fi[j8] = (_Float16)vi; fh[j8] = (_Float16)vh;
                }
                B2i[n][kb] = fi; B2h[n][kb] = fh;
            }
        }
        const float bl = ldf(blin, 0, isbf);
        float c2[4] = {0,0,0,0};

        #pragma unroll 2
        for (int k = 0; k <= T_LEN; ++k) {
            if (k >= 1) {
                const int rs1 = (k - 1) & 1;   // h1(k-1) + x/bias slots
                const int rs2 = k & 1;         // h2(k-2)
                const int ws2 = (k - 1) & 1;   // h2(k-1)
                const _Float16* h1p = &hx [rs1*HB + lid*ROWW + quad*8];
                const _Float16* h2p = &h2b[rs2*HB + lid*ROWW + quad*8];
                const f16x8 p0 = *(const f16x8*)(h1p);
                const f16x8 p1 = *(const f16x8*)(h1p + 32);
                const f16x8 q0 = *(const f16x8*)(h2p);
                const f16x8 q1 = *(const f16x8*)(h2p + 32);
                f32x4 acc[4];
                __builtin_amdgcn_s_setprio(1);
                #pragma unroll
                for (int n = 0; n < 4; ++n) {
                    f32x4 z = {0.0f, 0.0f, 0.0f, 0.0f};
                    z      = __builtin_amdgcn_mfma_f32_16x16x32_f16(p0, B2i[n][0], z, 0,0,0);
                    z      = __builtin_amdgcn_mfma_f32_16x16x32_f16(p1, B2i[n][1], z, 0,0,0);
                    z      = __builtin_amdgcn_mfma_f32_16x16x32_f16(q0, B2h[n][0], z, 0,0,0);
                    acc[n] = __builtin_amdgcn_mfma_f32_16x16x32_f16(q1, B2h[n][1], z, 0,0,0);
                }
                __builtin_amdgcn_s_setprio(0);
                if (ylane && k >= 2) {   // pad col: blin + Wlin.h2(k-2) = y[k-2]
                    #pragma unroll
                    for (int r = 0; r < 4; ++r)
                        store_y(outp, isbf, (b0 + quad*4 + r)*T_LEN + (k - 2), acc[3][r]);
                }
                float s[3][4];
                #pragma unroll
                for (int n = 0; n < 3; ++n) {
                    float d0 = 1.0f + __builtin_amdgcn_exp2f(acc[n][0]);
                    float d1 = 1.0f + __builtin_amdgcn_exp2f(acc[n][1]);
                    float d2 = 1.0f + __builtin_amdgcn_exp2f(acc[n][2]);
                    float d3 = 1.0f + __builtin_amdgcn_exp2f(acc[n][3]);
                    const float Ra = __builtin_amdgcn_rcpf(d0*d1);
                    const float Rb = __builtin_amdgcn_rcpf(d2*d3);
                    if (n == 2) {
                        s[n][0] = fmaf(2.0f, Ra*d1, -1.0f);
                        s[n][1] = fmaf(2.0f, Ra*d0, -1.0f);
                        s[n][2] = fmaf(2.0f, Rb*d3, -1.0f);
                        s[n][3] = fmaf(2.0f, Rb*d2, -1.0f);
                    } else {
                        s[n][0] = Ra*d1; s[n][1] = Ra*d0;
                        s[n][2] = Rb*d3; s[n][3] = Rb*d2;
                    }
                }
                float dox[4];
                #pragma unroll
                for (int r = 0; r < 4; ++r)
                    dox[r] = 1.0f + __builtin_amdgcn_exp2f(acc[3][r]);
                float m[4], ec[4];
                #pragma unroll
                for (int r = 0; r < 4; ++r) {
                    const float c = fmaf(s[1][r], c2[r], s[0][r]*s[2][r]);
                    c2[r] = c;
                    const float a = __builtin_amdgcn_fmed3f(-2.0f*LOG2E*c, -30.0f, 30.0f);
                    const float e = __builtin_amdgcn_exp2f(a);
                    ec[r] = e;
                    m[r]  = dox[r] * (1.0f + e);
                }
                const float Rc = __builtin_amdgcn_rcpf(m[0]*m[1]);
                const float Rd = __builtin_amdgcn_rcpf(m[2]*m[3]);
                float h[4];
                h[0] = (1.0f - ec[0]) * (Rc * m[1]);
                h[1] = (1.0f - ec[1]) * (Rc * m[0]);
                h[2] = (1.0f - ec[2]) * (Rd * m[3]);
                h[3] = (1.0f - ec[3]) * (Rd * m[2]);
                if (valid) {
                    #pragma unroll
                    for (int r = 0; r < 4; ++r)
                        h2b[ws2*HB + (quad*4 + r)*ROWW + jcol] = (_Float16)h[r];
                }
            }
            __syncthreads();
        }

        // ---- flush y[T-1] from final h2 (parity (T-1)&1) ----
        if (wv == 3) {
            const _Float16* h2p = &h2b[((T_LEN - 1) & 1)*HB + lid*ROWW + quad*8];
            const f16x8 q0 = *(const f16x8*)(h2p);
            const f16x8 q1 = *(const f16x8*)(h2p + 32);
            f32x4 z = {bl, bl, bl, bl};
            z = __builtin_amdgcn_mfma_f32_16x16x32_f16(q0, B2h[3][0], z, 0,0,0);
            z = __builtin_amdgcn_mfma_f32_16x16x32_f16(q1, B2h[3][1], z, 0,0,0);
            if (lid == 12) {
                #pragma unroll
                for (int r = 0; r < 4; ++r)
                    store_y(outp, isbf, (b0 + quad*4 + r)*T_LEN + (T_LEN - 1), z[r]);
            }
        }
    }
}

extern "C" void kernel_launch(void* const* d_in, const int* in_sizes, int n_in,
                              void* d_out, int out_size, void* d_ws, size_t ws_size,
                              hipStream_t stream) {
    (void)in_sizes; (void)n_in; (void)out_size; (void)d_ws; (void)ws_size;
    dim3 grid(B_TOT / MR), block(512);
    lstm2_kernel<<<grid, block, 0, stream>>>(
        d_in[0], d_in[1], d_in[2], d_in[3], d_in[4], d_in[5],
        d_in[6], d_in[7], d_in[8], d_in[9], d_in[10], d_out);
}

// Round 2
// 2452.271 us; speedup vs baseline: 1.0625x; 1.0240x over previous
//
#include <hip/hip_runtime.h>

// LSTM_RNN: B=8192, T=2048, H=51, 2-layer LSTM + linear head.
// R6: activation-math cycle diet (SIMD is issue-saturated: VALUBusy+MfmaUtil
// ~= 100% both prior rounds, trans ops ~60% of VALU time):
//  - fused i*g: sigma(i)*tanh(g) = (2-dg)/(di*dg), pair-rcp over q=di*dg
//    (-8 mul vs separate gate evaluation)
//  - batch-4 Montgomery rcp for sigma(f) (-1 rcp, +3 mul)
//  - cell state stored pre-scaled (C = -2*log2e*c); scale folds into the
//    fused-ig fma constant (-4 mul)
//  - L2-only med3 clamp on g-preact (+-30) keeps the ig pair-product < 2^127
// Trans 28->25/wave-step, regular VALU ~-13 ops. Everything else as R5:
// fp16 MFMA, x/bias folded into K-slots 51/52, fused o/tanh(c) output with
// pair-rcp, ROWW=72 LDS rows, producer-consumer wave split, s_setprio around
// MFMA, 1 barrier/step.

#define B_TOT 8192
#define T_LEN 2048
#define MR    16
#define ROWW  72            // f16 per row: [h 0..50][x 51][1.0 52][0 ..63][pad]
#define HB    (MR*ROWW)     // 1152 f16 per parity buffer

typedef _Float16 f16x8 __attribute__((ext_vector_type(8)));
typedef float    f32x4 __attribute__((ext_vector_type(4)));

#define LOG2E 1.4426950408889634f

static __device__ __forceinline__ float us2f(unsigned short u) {
    unsigned int w = ((unsigned int)u) << 16;
    float f; __builtin_memcpy(&f, &w, 4);
    return f;
}
// load f32 from f32 or bf16 global
static __device__ __forceinline__ float ldf(const void* p, int idx, bool isbf) {
    return isbf ? us2f(((const unsigned short*)p)[idx])
                : ((const float*)p)[idx];
}
static __device__ __forceinline__ void store_y(void* outp, bool isbf, int idx, float v) {
    if (isbf) {
        unsigned int u; __builtin_memcpy(&u, &v, 4);
        u = (u + 0x7FFFu + ((u >> 16) & 1u)) >> 16;
        ((unsigned short*)outp)[idx] = (unsigned short)u;
    } else {
        ((float*)outp)[idx] = v;
    }
}

// Shared LSTM activation + cell/h update.
// acc[n][r] = scaled pre-acts: n=0 i (-L*z), n=1 f (-L*z), n=2 g (-2L*z),
// n=3 o (-L*z). C[] holds the cell state pre-scaled by -2L. h[] out.
// CLAMP_G: clamp g-preact to +-30 (needed on L2 where |acc_g| can reach ~42,
// so the ig pair-product q0*q1 stays < 2^127).
template<bool CLAMP_G>
static __device__ __forceinline__ void lstm_act(const f32x4* acc, float* C, float* h) {
    float di[4], df[4], dg[4], dox[4];
    #pragma unroll
    for (int r = 0; r < 4; ++r) {
        di[r]  = 1.0f + __builtin_amdgcn_exp2f(acc[0][r]);
        df[r]  = 1.0f + __builtin_amdgcn_exp2f(acc[1][r]);
        float ag = acc[2][r];
        if (CLAMP_G) ag = __builtin_amdgcn_fmed3f(ag, -30.0f, 30.0f);
        dg[r]  = 1.0f + __builtin_amdgcn_exp2f(ag);
        dox[r] = 1.0f + __builtin_amdgcn_exp2f(acc[3][r]);
    }
    // fused sig[r] = -2L * sigma(i) * tanh(g) = (2L*dg - 4L) / (di*dg),
    // pair-rcp over q = di*dg  (bounds: L1 q<=2^36, L2 clamped q<=2^51)
    float q[4];
    #pragma unroll
    for (int r = 0; r < 4; ++r) q[r] = di[r]*dg[r];
    const float Ri0 = __builtin_amdgcn_rcpf(q[0]*q[1]);
    const float Ri1 = __builtin_amdgcn_rcpf(q[2]*q[3]);
    float sig[4];
    sig[0] = fmaf(2.0f*LOG2E, dg[0], -4.0f*LOG2E) * (Ri0*q[1]);
    sig[1] = fmaf(2.0f*LOG2E, dg[1], -4.0f*LOG2E) * (Ri0*q[0]);
    sig[2] = fmaf(2.0f*LOG2E, dg[2], -4.0f*LOG2E) * (Ri1*q[3]);
    sig[3] = fmaf(2.0f*LOG2E, dg[3], -4.0f*LOG2E) * (Ri1*q[2]);
    // sigma(f) via batch-4 Montgomery rcp (df^4 <= 2^84, safe)
    const float pf01 = df[0]*df[1], pf23 = df[2]*df[3];
    const float Rf   = __builtin_amdgcn_rcpf(pf01*pf23);
    const float Rf01 = Rf*pf23, Rf23 = Rf*pf01;
    float sf[4];
    sf[0] = Rf01*df[1]; sf[1] = Rf01*df[0];
    sf[2] = Rf23*df[3]; sf[3] = Rf23*df[2];
    // C update (pre-scaled by -2L) + fused sigma(o)*tanh(c) output
    float tt[4], m[4];
    #pragma unroll
    for (int r = 0; r < 4; ++r) {
        const float Cn = fmaf(sf[r], C[r], sig[r]);
        C[r] = Cn;
        const float a = __builtin_amdgcn_fmed3f(Cn, -30.0f, 30.0f);
        const float e = __builtin_amdgcn_exp2f(a);
        tt[r] = 1.0f + e;          // 1 + e^{-2c}
        m[r]  = dox[r] * tt[r];    // (1+e^{-o})(1+e^{-2c}) <= 2^52
    }
    const float Rc = __builtin_amdgcn_rcpf(m[0]*m[1]);
    const float Rd = __builtin_amdgcn_rcpf(m[2]*m[3]);
    h[0] = (2.0f - tt[0]) * (Rc*m[1]);
    h[1] = (2.0f - tt[1]) * (Rc*m[0]);
    h[2] = (2.0f - tt[2]) * (Rd*m[3]);
    h[3] = (2.0f - tt[3]) * (Rd*m[2]);
}

__global__ __launch_bounds__(512, 4)
void lstm2_kernel(const void* __restrict__ xin,
                  const void* __restrict__ Wih1, const void* __restrict__ Whh1,
                  const void* __restrict__ bih1, const void* __restrict__ bhh1,
                  const void* __restrict__ Wih2, const void* __restrict__ Whh2,
                  const void* __restrict__ bih2, const void* __restrict__ bhh2,
                  const void* __restrict__ Wlin, const void* __restrict__ blin,
                  void* __restrict__ outp)
{
    const int tid  = threadIdx.x;
    const int wset = tid >> 8;         // 0: layer-1 waves, 1: layer-2 waves
    const int wv   = (tid >> 6) & 3;   // j-slice within set
    const int ln   = tid & 63;
    const int lid  = ln & 15;
    const int quad = ln >> 4;
    const int b0   = blockIdx.x * MR;
    const int jcol = 13*wv + lid;
    const bool valid = (lid < 13) && (jcol < 51);
    const bool ylane = (wv == 3) && (lid == 12);   // pad col 51 -> y head

    __shared__ alignas(16) _Float16 hx [2*HB];   // h1 ping-pong + x/1.0 K-slots
    __shared__ alignas(16) _Float16 h2b[2*HB];   // h2 ping-pong

    // ---- dtype sniff (f32 vs bf16 globals), block-uniform ----
    bool isbf;
    {
        const unsigned short* xu = (const unsigned short*)xin;
        int cnt = 0;
        #pragma unroll
        for (int i = 0; i < 64; i += 2) {
            unsigned e = (xu[i] >> 7) & 0xFFu;
            cnt += (e >= 115u && e <= 131u) ? 1 : 0;
        }
        isbf = (cnt >= 16);
    }

    // ---- init LDS ----
    for (int i = tid; i < 2*HB; i += 512) {
        hx[i]  = (_Float16)0.0f;
        h2b[i] = (_Float16)0.0f;
    }
    __syncthreads();
    if (tid < MR) {
        hx[0*HB + tid*ROWW + 52] = (_Float16)1.0f;   // bias slot, both parities
        hx[1*HB + tid*ROWW + 52] = (_Float16)1.0f;
        hx[1*HB + tid*ROWW + 51] = (_Float16)ldf(xin, (b0 + tid)*T_LEN, isbf);
    }
    __syncthreads();

    if (wset == 0) {
        // ================= LAYER-1 WAVES =================
        // B-frag: k<51 -> sn*Whh1 ; k==51 -> sn*Wih1 (x slot) ; k==52 -> sn*bias
        f16x8 B1[4][2];
        #pragma unroll
        for (int n = 0; n < 4; ++n) {
            const int g = 51*n + jcol;
            const float sn = (n == 2) ? -2.0f*LOG2E : -LOG2E;
            #pragma unroll
            for (int kb = 0; kb < 2; ++kb) {
                f16x8 f;
                #pragma unroll
                for (int j8 = 0; j8 < 8; ++j8) {
                    const int k = kb*32 + quad*8 + j8;
                    float v = 0.0f;
                    if (valid) {
                        if (k < 51)       v = sn * ldf(Whh1, g*51 + k, isbf);
                        else if (k == 51) v = sn * ldf(Wih1, g, isbf);
                        else if (k == 52) v = sn * (ldf(bih1, g, isbf) + ldf(bhh1, g, isbf));
                    }
                    f[j8] = (_Float16)v;
                }
                B1[n][kb] = f;
            }
        }
        float c1[4] = {0,0,0,0};   // pre-scaled cell state (-2L*c)

        #pragma unroll 2
        for (int k = 0; k <= T_LEN; ++k) {
            if (k < T_LEN) {
                const int rs = (k - 1) & 1, ws = k & 1;
                // early x(k+1) prefetch (wave 0 lanes 0..15)
                const bool xl = (tid < MR) && (k + 1 < T_LEN);
                float xnext = 0.0f;
                if (xl) xnext = ldf(xin, (b0 + tid)*T_LEN + k + 1, isbf);

                const _Float16* hp = &hx[rs*HB + lid*ROWW + quad*8];
                const f16x8 a0 = *(const f16x8*)(hp);
                const f16x8 a1 = *(const f16x8*)(hp + 32);
                f32x4 acc[4];
                __builtin_amdgcn_s_setprio(1);
                #pragma unroll
                for (int n = 0; n < 4; ++n) {
                    f32x4 z = {0.0f, 0.0f, 0.0f, 0.0f};
                    z      = __builtin_amdgcn_mfma_f32_16x16x32_f16(a0, B1[n][0], z, 0,0,0);
                    acc[n] = __builtin_amdgcn_mfma_f32_16x16x32_f16(a1, B1[n][1], z, 0,0,0);
                }
                __builtin_amdgcn_s_setprio(0);
                float h[4];
                lstm_act<false>(acc, c1, h);
                if (valid) {
                    #pragma unroll
                    for (int r = 0; r < 4; ++r)
                        hx[ws*HB + (quad*4 + r)*ROWW + jcol] = (_Float16)h[r];
                }
                if (xl) hx[ws*HB + tid*ROWW + 51] = (_Float16)xnext;
            }
            __syncthreads();
        }
    } else {
        // ================= LAYER-2 WAVES =================
        // B2i over h1-path A (k<51: Wih2; k==51: 0 kills x slot; k==52: bias
        // [or blin on y pad col]); B2h over h2-path A (k<51: Whh2 [or Wlin]).
        f16x8 B2i[4][2], B2h[4][2];
        #pragma unroll
        for (int n = 0; n < 4; ++n) {
            const int g = 51*n + jcol;
            const float sn = (n == 2) ? -2.0f*LOG2E : -LOG2E;
            #pragma unroll
            for (int kb = 0; kb < 2; ++kb) {
                f16x8 fi, fh;
                #pragma unroll
                for (int j8 = 0; j8 < 8; ++j8) {
                    const int k = kb*32 + quad*8 + j8;
                    float vi = 0.0f, vh = 0.0f;
                    if (valid) {
                        if (k < 51) {
                            vi = sn * ldf(Wih2, g*51 + k, isbf);
                            vh = sn * ldf(Whh2, g*51 + k, isbf);
                        } else if (k == 52) {
                            vi = sn * (ldf(bih2, g, isbf) + ldf(bhh2, g, isbf));
                        }
                    } else if (ylane && n == 3) {
                        if (k < 51)       vh = ldf(Wlin, k, isbf);
                        else if (k == 52) vi = ldf(blin, 0, isbf);
                    }
                    fi[j8] = (_Float16)vi; fh[j8] = (_Float16)vh;
                }
                B2i[n][kb] = fi; B2h[n][kb] = fh;
            }
        }
        const float bl = ldf(blin, 0, isbf);
        float c2[4] = {0,0,0,0};   // pre-scaled cell state (-2L*c)

        #pragma unroll 2
        for (int k = 0; k <= T_LEN; ++k) {
            if (k >= 1) {
                const int rs1 = (k - 1) & 1;   // h1(k-1) + x/bias slots
                const int rs2 = k & 1;         // h2(k-2)
                const int ws2 = (k - 1) & 1;   // h2(k-1)
                const _Float16* h1p = &hx [rs1*HB + lid*ROWW + quad*8];
                const _Float16* h2p = &h2b[rs2*HB + lid*ROWW + quad*8];
                const f16x8 p0 = *(const f16x8*)(h1p);
                const f16x8 p1 = *(const f16x8*)(h1p + 32);
                const f16x8 q0 = *(const f16x8*)(h2p);
                const f16x8 q1 = *(const f16x8*)(h2p + 32);
                f32x4 acc[4];
                __builtin_amdgcn_s_setprio(1);
                #pragma unroll
                for (int n = 0; n < 4; ++n) {
                    f32x4 z = {0.0f, 0.0f, 0.0f, 0.0f};
                    z      = __builtin_amdgcn_mfma_f32_16x16x32_f16(p0, B2i[n][0], z, 0,0,0);
                    z      = __builtin_amdgcn_mfma_f32_16x16x32_f16(p1, B2i[n][1], z, 0,0,0);
                    z      = __builtin_amdgcn_mfma_f32_16x16x32_f16(q0, B2h[n][0], z, 0,0,0);
                    acc[n] = __builtin_amdgcn_mfma_f32_16x16x32_f16(q1, B2h[n][1], z, 0,0,0);
                }
                __builtin_amdgcn_s_setprio(0);
                if (ylane && k >= 2) {   // pad col: blin + Wlin.h2(k-2) = y[k-2]
                    #pragma unroll
                    for (int r = 0; r < 4; ++r)
                        store_y(outp, isbf, (b0 + quad*4 + r)*T_LEN + (k - 2), acc[3][r]);
                }
                float h[4];
                lstm_act<true>(acc, c2, h);
                if (valid) {
                    #pragma unroll
                    for (int r = 0; r < 4; ++r)
                        h2b[ws2*HB + (quad*4 + r)*ROWW + jcol] = (_Float16)h[r];
                }
            }
            __syncthreads();
        }

        // ---- flush y[T-1] from final h2 (parity (T-1)&1) ----
        if (wv == 3) {
            const _Float16* h2p = &h2b[((T_LEN - 1) & 1)*HB + lid*ROWW + quad*8];
            const f16x8 q0 = *(const f16x8*)(h2p);
            const f16x8 q1 = *(const f16x8*)(h2p + 32);
            f32x4 z = {bl, bl, bl, bl};
            z = __builtin_amdgcn_mfma_f32_16x16x32_f16(q0, B2h[3][0], z, 0,0,0);
            z = __builtin_amdgcn_mfma_f32_16x16x32_f16(q1, B2h[3][1], z, 0,0,0);
            if (lid == 12) {
                #pragma unroll
                for (int r = 0; r < 4; ++r)
                    store_y(outp, isbf, (b0 + quad*4 + r)*T_LEN + (T_LEN - 1), z[r]);
            }
        }
    }
}

extern "C" void kernel_launch(void* const* d_in, const int* in_sizes, int n_in,
                              void* d_out, int out_size, void* d_ws, size_t ws_size,
                              hipStream_t stream) {
    (void)in_sizes; (void)n_in; (void)out_size; (void)d_ws; (void)ws_size;
    dim3 grid(B_TOT / MR), block(512);
    lstm2_kernel<<<grid, block, 0, stream>>>(
        d_in[0], d_in[1], d_in[2], d_in[3], d_in[4], d_in[5],
        d_in[6], d_in[7], d_in[8], d_in[9], d_in[10], d_out);
}

// Round 3
// 2319.381 us; speedup vs baseline: 1.1233x; 1.0573x over previous
//
#include <hip/hip_runtime.h>

// LSTM_RNN: B=8192, T=2048, H=51, 2-layer LSTM + linear head.
// R7: packed-FP32 activation math. SIMD issue port is saturated
// (VALUBusy+MfmaUtil ~= 102% for 3 rounds); trans count is at the
// 5-exp/element floor, so this round halves the REGULAR f32 op count by
// rewriting lstm_act on float2 (ext_vector) row-pairs -> LLVM selects
// v_pk_{fma,mul,add}_f32 (full-rate dual f32, CDNA2+). exp2/rcp/med3 stay
// scalar (no packed trans). Bit-identical arithmetic. Everything else as
// R6: fused i*g pair-rcp, batch-4 Montgomery rcp for sigma(f), pre-scaled
// cell state (-2L*c), fused sigma(o)*tanh(c) output, fp16 MFMA with x/bias
// K-slots, ROWW=72, producer-consumer wave split, s_setprio, 1 barrier/step.

#define B_TOT 8192
#define T_LEN 2048
#define MR    16
#define ROWW  72            // f16 per row: [h 0..50][x 51][1.0 52][0 ..63][pad]
#define HB    (MR*ROWW)     // 1152 f16 per parity buffer

typedef _Float16 f16x8 __attribute__((ext_vector_type(8)));
typedef float    f32x4 __attribute__((ext_vector_type(4)));
typedef float    f32x2 __attribute__((ext_vector_type(2)));

#define LOG2E 1.4426950408889634f

static __device__ __forceinline__ float us2f(unsigned short u) {
    unsigned int w = ((unsigned int)u) << 16;
    float f; __builtin_memcpy(&f, &w, 4);
    return f;
}
// load f32 from f32 or bf16 global
static __device__ __forceinline__ float ldf(const void* p, int idx, bool isbf) {
    return isbf ? us2f(((const unsigned short*)p)[idx])
                : ((const float*)p)[idx];
}
static __device__ __forceinline__ void store_y(void* outp, bool isbf, int idx, float v) {
    if (isbf) {
        unsigned int u; __builtin_memcpy(&u, &v, 4);
        u = (u + 0x7FFFu + ((u >> 16) & 1u)) >> 16;
        ((unsigned short*)outp)[idx] = (unsigned short)u;
    } else {
        ((float*)outp)[idx] = v;
    }
}

// Shared LSTM activation + cell/h update on packed row-pairs.
// acc[n][r] = scaled pre-acts: n=0 i (-L*z), n=1 f (-L*z), n=2 g (-2L*z),
// n=3 o (-L*z). C[p] holds cell state for rows {2p,2p+1}, pre-scaled by -2L.
// h[p] out, same pairing. CLAMP_G: clamp g-preact to +-30 (L2 only; keeps
// the ig pair-product < 2^127).
template<bool CLAMP_G>
static __device__ __forceinline__ void lstm_act(const f32x4* acc, f32x2* C, f32x2* h) {
    f32x2 di[2], df[2], dg[2], dox[2];
    #pragma unroll
    for (int p = 0; p < 2; ++p) {
        f32x2 ei, ef, eg, eo;
        #pragma unroll
        for (int e = 0; e < 2; ++e) {
            const int r = 2*p + e;
            ei[e] = __builtin_amdgcn_exp2f(acc[0][r]);
            ef[e] = __builtin_amdgcn_exp2f(acc[1][r]);
            float ag = acc[2][r];
            if (CLAMP_G) ag = __builtin_amdgcn_fmed3f(ag, -30.0f, 30.0f);
            eg[e] = __builtin_amdgcn_exp2f(ag);
            eo[e] = __builtin_amdgcn_exp2f(acc[3][r]);
        }
        di[p]  = ei + 1.0f;
        df[p]  = ef + 1.0f;
        dg[p]  = eg + 1.0f;
        dox[p] = eo + 1.0f;
    }
    // fused sig = -2L*sigma(i)*tanh(g) = (2L*dg - 4L)/(di*dg), pair-rcp
    // over q = di*dg (bounds: L1 q<=2^36, L2 clamped q<=2^51)
    f32x2 q[2], sig[2];
    q[0] = di[0]*dg[0];
    q[1] = di[1]*dg[1];
    const float Ri0 = __builtin_amdgcn_rcpf(q[0].x*q[0].y);
    const float Ri1 = __builtin_amdgcn_rcpf(q[1].x*q[1].y);
    sig[0] = (dg[0]*(2.0f*LOG2E) + (-4.0f*LOG2E)) * (q[0].yx * Ri0);
    sig[1] = (dg[1]*(2.0f*LOG2E) + (-4.0f*LOG2E)) * (q[1].yx * Ri1);
    // sigma(f) via batch-4 Montgomery rcp (df^4 <= 2^84, safe)
    const float pf01 = df[0].x*df[0].y;
    const float pf23 = df[1].x*df[1].y;
    const float Rf   = __builtin_amdgcn_rcpf(pf01*pf23);
    const f32x2 sf0 = df[0].yx * (Rf*pf23);
    const f32x2 sf1 = df[1].yx * (Rf*pf01);
    // C update (pre-scaled by -2L) + fused sigma(o)*tanh(c) output
    f32x2 tt[2], m[2];
    {
        const f32x2 Cn = sf0*C[0] + sig[0];
        C[0] = Cn;
        f32x2 e2;
        e2.x = __builtin_amdgcn_exp2f(__builtin_amdgcn_fmed3f(Cn.x, -30.0f, 30.0f));
        e2.y = __builtin_amdgcn_exp2f(__builtin_amdgcn_fmed3f(Cn.y, -30.0f, 30.0f));
        tt[0] = e2 + 1.0f;           // 1 + e^{-2c}
        m[0]  = dox[0]*tt[0];        // (1+e^{-o})(1+e^{-2c}) <= 2^52
    }
    {
        const f32x2 Cn = sf1*C[1] + sig[1];
        C[1] = Cn;
        f32x2 e2;
        e2.x = __builtin_amdgcn_exp2f(__builtin_amdgcn_fmed3f(Cn.x, -30.0f, 30.0f));
        e2.y = __builtin_amdgcn_exp2f(__builtin_amdgcn_fmed3f(Cn.y, -30.0f, 30.0f));
        tt[1] = e2 + 1.0f;
        m[1]  = dox[1]*tt[1];
    }
    const float Rc = __builtin_amdgcn_rcpf(m[0].x*m[0].y);
    const float Rd = __builtin_amdgcn_rcpf(m[1].x*m[1].y);
    h[0] = (2.0f - tt[0]) * (m[0].yx * Rc);
    h[1] = (2.0f - tt[1]) * (m[1].yx * Rd);
}

__global__ __launch_bounds__(512, 4)
void lstm2_kernel(const void* __restrict__ xin,
                  const void* __restrict__ Wih1, const void* __restrict__ Whh1,
                  const void* __restrict__ bih1, const void* __restrict__ bhh1,
                  const void* __restrict__ Wih2, const void* __restrict__ Whh2,
                  const void* __restrict__ bih2, const void* __restrict__ bhh2,
                  const void* __restrict__ Wlin, const void* __restrict__ blin,
                  void* __restrict__ outp)
{
    const int tid  = threadIdx.x;
    const int wset = tid >> 8;         // 0: layer-1 waves, 1: layer-2 waves
    const int wv   = (tid >> 6) & 3;   // j-slice within set
    const int ln   = tid & 63;
    const int lid  = ln & 15;
    const int quad = ln >> 4;
    const int b0   = blockIdx.x * MR;
    const int jcol = 13*wv + lid;
    const bool valid = (lid < 13) && (jcol < 51);
    const bool ylane = (wv == 3) && (lid == 12);   // pad col 51 -> y head

    __shared__ alignas(16) _Float16 hx [2*HB];   // h1 ping-pong + x/1.0 K-slots
    __shared__ alignas(16) _Float16 h2b[2*HB];   // h2 ping-pong

    // ---- dtype sniff (f32 vs bf16 globals), block-uniform ----
    bool isbf;
    {
        const unsigned short* xu = (const unsigned short*)xin;
        int cnt = 0;
        #pragma unroll
        for (int i = 0; i < 64; i += 2) {
            unsigned e = (xu[i] >> 7) & 0xFFu;
            cnt += (e >= 115u && e <= 131u) ? 1 : 0;
        }
        isbf = (cnt >= 16);
    }

    // ---- init LDS ----
    for (int i = tid; i < 2*HB; i += 512) {
        hx[i]  = (_Float16)0.0f;
        h2b[i] = (_Float16)0.0f;
    }
    __syncthreads();
    if (tid < MR) {
        hx[0*HB + tid*ROWW + 52] = (_Float16)1.0f;   // bias slot, both parities
        hx[1*HB + tid*ROWW + 52] = (_Float16)1.0f;
        hx[1*HB + tid*ROWW + 51] = (_Float16)ldf(xin, (b0 + tid)*T_LEN, isbf);
    }
    __syncthreads();

    if (wset == 0) {
        // ================= LAYER-1 WAVES =================
        // B-frag: k<51 -> sn*Whh1 ; k==51 -> sn*Wih1 (x slot) ; k==52 -> sn*bias
        f16x8 B1[4][2];
        #pragma unroll
        for (int n = 0; n < 4; ++n) {
            const int g = 51*n + jcol;
            const float sn = (n == 2) ? -2.0f*LOG2E : -LOG2E;
            #pragma unroll
            for (int kb = 0; kb < 2; ++kb) {
                f16x8 f;
                #pragma unroll
                for (int j8 = 0; j8 < 8; ++j8) {
                    const int k = kb*32 + quad*8 + j8;
                    float v = 0.0f;
                    if (valid) {
                        if (k < 51)       v = sn * ldf(Whh1, g*51 + k, isbf);
                        else if (k == 51) v = sn * ldf(Wih1, g, isbf);
                        else if (k == 52) v = sn * (ldf(bih1, g, isbf) + ldf(bhh1, g, isbf));
                    }
                    f[j8] = (_Float16)v;
                }
                B1[n][kb] = f;
            }
        }
        f32x2 c1[2] = {{0.0f, 0.0f}, {0.0f, 0.0f}};   // pre-scaled cell (-2L*c)

        #pragma unroll 2
        for (int k = 0; k <= T_LEN; ++k) {
            if (k < T_LEN) {
                const int rs = (k - 1) & 1, ws = k & 1;
                // early x(k+1) prefetch (wave 0 lanes 0..15)
                const bool xl = (tid < MR) && (k + 1 < T_LEN);
                float xnext = 0.0f;
                if (xl) xnext = ldf(xin, (b0 + tid)*T_LEN + k + 1, isbf);

                const _Float16* hp = &hx[rs*HB + lid*ROWW + quad*8];
                const f16x8 a0 = *(const f16x8*)(hp);
                const f16x8 a1 = *(const f16x8*)(hp + 32);
                f32x4 acc[4];
                __builtin_amdgcn_s_setprio(1);
                #pragma unroll
                for (int n = 0; n < 4; ++n) {
                    f32x4 z = {0.0f, 0.0f, 0.0f, 0.0f};
                    z      = __builtin_amdgcn_mfma_f32_16x16x32_f16(a0, B1[n][0], z, 0,0,0);
                    acc[n] = __builtin_amdgcn_mfma_f32_16x16x32_f16(a1, B1[n][1], z, 0,0,0);
                }
                __builtin_amdgcn_s_setprio(0);
                f32x2 h[2];
                lstm_act<false>(acc, c1, h);
                if (valid) {
                    _Float16* hw = &hx[ws*HB + (quad*4)*ROWW + jcol];
                    hw[0*ROWW] = (_Float16)h[0].x;
                    hw[1*ROWW] = (_Float16)h[0].y;
                    hw[2*ROWW] = (_Float16)h[1].x;
                    hw[3*ROWW] = (_Float16)h[1].y;
                }
                if (xl) hx[ws*HB + tid*ROWW + 51] = (_Float16)xnext;
            }
            __syncthreads();
        }
    } else {
        // ================= LAYER-2 WAVES =================
        // B2i over h1-path A (k<51: Wih2; k==51: 0 kills x slot; k==52: bias
        // [or blin on y pad col]); B2h over h2-path A (k<51: Whh2 [or Wlin]).
        f16x8 B2i[4][2], B2h[4][2];
        #pragma unroll
        for (int n = 0; n < 4; ++n) {
            const int g = 51*n + jcol;
            const float sn = (n == 2) ? -2.0f*LOG2E : -LOG2E;
            #pragma unroll
            for (int kb = 0; kb < 2; ++kb) {
                f16x8 fi, fh;
                #pragma unroll
                for (int j8 = 0; j8 < 8; ++j8) {
                    const int k = kb*32 + quad*8 + j8;
                    float vi = 0.0f, vh = 0.0f;
                    if (valid) {
                        if (k < 51) {
                            vi = sn * ldf(Wih2, g*51 + k, isbf);
                            vh = sn * ldf(Whh2, g*51 + k, isbf);
                        } else if (k == 52) {
                            vi = sn * (ldf(bih2, g, isbf) + ldf(bhh2, g, isbf));
                        }
                    } else if (ylane && n == 3) {
                        if (k < 51)       vh = ldf(Wlin, k, isbf);
                        else if (k == 52) vi = ldf(blin, 0, isbf);
                    }
                    fi[j8] = (_Float16)vi; fh[j8] = (_Float16)vh;
                }
                B2i[n][kb] = fi; B2h[n][kb] = fh;
            }
        }
        const float bl = ldf(blin, 0, isbf);
        f32x2 c2[2] = {{0.0f, 0.0f}, {0.0f, 0.0f}};   // pre-scaled cell (-2L*c)

        #pragma unroll 2
        for (int k = 0; k <= T_LEN; ++k) {
            if (k >= 1) {
                const int rs1 = (k - 1) & 1;   // h1(k-1) + x/bias slots
                const int rs2 = k & 1;         // h2(k-2)
                const int ws2 = (k - 1) & 1;   // h2(k-1)
                const _Float16* h1p = &hx [rs1*HB + lid*ROWW + quad*8];
                const _Float16* h2p = &h2b[rs2*HB + lid*ROWW + quad*8];
                const f16x8 p0 = *(const f16x8*)(h1p);
                const f16x8 p1 = *(const f16x8*)(h1p + 32);
                const f16x8 q0 = *(const f16x8*)(h2p);
                const f16x8 q1 = *(const f16x8*)(h2p + 32);
                f32x4 acc[4];
                __builtin_amdgcn_s_setprio(1);
                #pragma unroll
                for (int n = 0; n < 4; ++n) {
                    f32x4 z = {0.0f, 0.0f, 0.0f, 0.0f};
                    z      = __builtin_amdgcn_mfma_f32_16x16x32_f16(p0, B2i[n][0], z, 0,0,0);
                    z      = __builtin_amdgcn_mfma_f32_16x16x32_f16(p1, B2i[n][1], z, 0,0,0);
                    z      = __builtin_amdgcn_mfma_f32_16x16x32_f16(q0, B2h[n][0], z, 0,0,0);
                    acc[n] = __builtin_amdgcn_mfma_f32_16x16x32_f16(q1, B2h[n][1], z, 0,0,0);
                }
                __builtin_amdgcn_s_setprio(0);
                if (ylane && k >= 2) {   // pad col: blin + Wlin.h2(k-2) = y[k-2]
                    #pragma unroll
                    for (int r = 0; r < 4; ++r)
                        store_y(outp, isbf, (b0 + quad*4 + r)*T_LEN + (k - 2), acc[3][r]);
                }
                f32x2 h[2];
                lstm_act<true>(acc, c2, h);
                if (valid) {
                    _Float16* hw = &h2b[ws2*HB + (quad*4)*ROWW + jcol];
                    hw[0*ROWW] = (_Float16)h[0].x;
                    hw[1*ROWW] = (_Float16)h[0].y;
                    hw[2*ROWW] = (_Float16)h[1].x;
                    hw[3*ROWW] = (_Float16)h[1].y;
                }
            }
            __syncthreads();
        }

        // ---- flush y[T-1] from final h2 (parity (T-1)&1) ----
        if (wv == 3) {
            const _Float16* h2p = &h2b[((T_LEN - 1) & 1)*HB + lid*ROWW + quad*8];
            const f16x8 q0 = *(const f16x8*)(h2p);
            const f16x8 q1 = *(const f16x8*)(h2p + 32);
            f32x4 z = {bl, bl, bl, bl};
            z = __builtin_amdgcn_mfma_f32_16x16x32_f16(q0, B2h[3][0], z, 0,0,0);
            z = __builtin_amdgcn_mfma_f32_16x16x32_f16(q1, B2h[3][1], z, 0,0,0);
            if (lid == 12) {
                #pragma unroll
                for (int r = 0; r < 4; ++r)
                    store_y(outp, isbf, (b0 + quad*4 + r)*T_LEN + (T_LEN - 1), z[r]);
            }
        }
    }
}

extern "C" void kernel_launch(void* const* d_in, const int* in_sizes, int n_in,
                              void* d_out, int out_size, void* d_ws, size_t ws_size,
                              hipStream_t stream) {
    (void)in_sizes; (void)n_in; (void)out_size; (void)d_ws; (void)ws_size;
    dim3 grid(B_TOT / MR), block(512);
    lstm2_kernel<<<grid, block, 0, stream>>>(
        d_in[0], d_in[1], d_in[2], d_in[3], d_in[4], d_in[5],
        d_in[6], d_in[7], d_in[8], d_in[9], d_in[10], d_out);
}